// Round 16
// baseline (1009.944 us; speedup 1.0000x reference)
//
#include <hip/hip_runtime.h>
#include <stdint.h>

#define B_ 1024
#define T_ 512
#define F_ 64
#define H_ 32
#define G_ 128  // 4H

typedef __attribute__((ext_vector_type(8))) short bf16x8;
typedef __attribute__((ext_vector_type(4))) float f32x4;
typedef __attribute__((ext_vector_type(4))) unsigned int u32x4;

__device__ __forceinline__ uint32_t bf16r(float f) {
  uint32_t u = __builtin_bit_cast(uint32_t, f);
  return (u + 0x7fffu + ((u >> 16) & 1u)) >> 16;  // RNE bf16
}
__device__ __forceinline__ float fsig(float x) { return 1.f / (1.f + __expf(-x)); }
__device__ __forceinline__ float ftanh(float x) { return 2.f / (1.f + __expf(-2.f * x)) - 1.f; }
__device__ __forceinline__ float bflo(uint32_t d) { return __builtin_bit_cast(float, d << 16); }
__device__ __forceinline__ float bfhi(uint32_t d) { return __builtin_bit_cast(float, d & 0xffff0000u); }

#define MFMA16(a, b, c) __builtin_amdgcn_mfma_f32_16x16x32_bf16((a), (b), (c), 0, 0, 0)

// ---------------------------------------------------------------------------
// K1 (MFMA, unchanged — verified r6/r7): xg = pack_bf16(tanh(x@Wenc+benc)@kern+bias)
// ---------------------------------------------------------------------------
__global__ __launch_bounds__(256, 3) void k1_mfma(
    const float* __restrict__ x, const float* __restrict__ Wenc,
    const float* __restrict__ benc, const float* __restrict__ kern,
    const float* __restrict__ bias, uint32_t* __restrict__ xg) {
  __shared__ unsigned short sWt[64 * 72];   // Wenc^T bf16 [n][k], stride 72
  __shared__ unsigned short sKt[128 * 72];  // kern^T bf16 [n][k]
  __shared__ unsigned short sE[128 * 72];   // enc bf16 [row][k]
  const int tid = threadIdx.x;
  const int lane = tid & 63;
  const int w = tid >> 6;       // wave 0..3 -> rows w*32..w*32+31
  const int m = lane & 15;
  const int g = lane >> 4;      // 0..3
  const int r0 = blockIdx.x * 128;

  {  // stage Wenc^T and kern^T as bf16 (one-time)
    const int r = tid & 63;
    const int c0 = (tid >> 6) * 16;
#pragma unroll
    for (int q = 0; q < 4; ++q) {
      float4 v = *(const float4*)(Wenc + (size_t)r * F_ + c0 + q * 4);
      sWt[(c0 + q * 4 + 0) * 72 + r] = (unsigned short)bf16r(v.x);
      sWt[(c0 + q * 4 + 1) * 72 + r] = (unsigned short)bf16r(v.y);
      sWt[(c0 + q * 4 + 2) * 72 + r] = (unsigned short)bf16r(v.z);
      sWt[(c0 + q * 4 + 3) * 72 + r] = (unsigned short)bf16r(v.w);
    }
    const int d0 = (tid >> 6) * 32;
#pragma unroll
    for (int q = 0; q < 8; ++q) {
      float4 v = *(const float4*)(kern + (size_t)r * G_ + d0 + q * 4);
      sKt[(d0 + q * 4 + 0) * 72 + r] = (unsigned short)bf16r(v.x);
      sKt[(d0 + q * 4 + 1) * 72 + r] = (unsigned short)bf16r(v.y);
      sKt[(d0 + q * 4 + 2) * 72 + r] = (unsigned short)bf16r(v.z);
      sKt[(d0 + q * 4 + 3) * 72 + r] = (unsigned short)bf16r(v.w);
    }
  }
  __syncthreads();

  bf16x8 a[2][2];
#pragma unroll
  for (int rt = 0; rt < 2; ++rt)
#pragma unroll
    for (int kh = 0; kh < 2; ++kh) {
      const float* xr = x + (size_t)(r0 + w * 32 + rt * 16 + m) * F_ + kh * 32 + g * 8;
      float4 v0 = ((const float4*)xr)[0];
      float4 v1 = ((const float4*)xr)[1];
      bf16x8 t;
      t[0] = (short)bf16r(v0.x); t[1] = (short)bf16r(v0.y);
      t[2] = (short)bf16r(v0.z); t[3] = (short)bf16r(v0.w);
      t[4] = (short)bf16r(v1.x); t[5] = (short)bf16r(v1.y);
      t[6] = (short)bf16r(v1.z); t[7] = (short)bf16r(v1.w);
      a[rt][kh] = t;
    }

#pragma unroll
  for (int ct = 0; ct < 4; ++ct) {
    float be = benc[ct * 16 + m];
    f32x4 acc0 = {be, be, be, be};
    f32x4 acc1 = {be, be, be, be};
    bf16x8 b0 = *(const bf16x8*)&sWt[(ct * 16 + m) * 72 + g * 8];
    bf16x8 b1 = *(const bf16x8*)&sWt[(ct * 16 + m) * 72 + 32 + g * 8];
    acc0 = MFMA16(a[0][0], b0, acc0);
    acc0 = MFMA16(a[0][1], b1, acc0);
    acc1 = MFMA16(a[1][0], b0, acc1);
    acc1 = MFMA16(a[1][1], b1, acc1);
#pragma unroll
    for (int r4 = 0; r4 < 4; ++r4) {
      sE[(w * 32 + g * 4 + r4) * 72 + ct * 16 + m] =
          (unsigned short)bf16r(ftanh(acc0[r4]));
      sE[(w * 32 + 16 + g * 4 + r4) * 72 + ct * 16 + m] =
          (unsigned short)bf16r(ftanh(acc1[r4]));
    }
  }
  __syncthreads();

  bf16x8 e[2][2];
#pragma unroll
  for (int rt = 0; rt < 2; ++rt)
#pragma unroll
    for (int kh = 0; kh < 2; ++kh)
      e[rt][kh] = *(const bf16x8*)&sE[(w * 32 + rt * 16 + m) * 72 + kh * 32 + g * 8];

#pragma unroll
  for (int ctp = 0; ctp < 4; ++ctp) {
    float blo = bias[ctp * 16 + m];
    float bhi = bias[64 + ctp * 16 + m];
    f32x4 lo0 = {blo, blo, blo, blo}, lo1 = {blo, blo, blo, blo};
    f32x4 hi0 = {bhi, bhi, bhi, bhi}, hi1 = {bhi, bhi, bhi, bhi};
    bf16x8 bl0 = *(const bf16x8*)&sKt[(ctp * 16 + m) * 72 + g * 8];
    bf16x8 bl1 = *(const bf16x8*)&sKt[(ctp * 16 + m) * 72 + 32 + g * 8];
    bf16x8 bh0 = *(const bf16x8*)&sKt[(64 + ctp * 16 + m) * 72 + g * 8];
    bf16x8 bh1 = *(const bf16x8*)&sKt[(64 + ctp * 16 + m) * 72 + 32 + g * 8];
    lo0 = MFMA16(e[0][0], bl0, lo0);  lo0 = MFMA16(e[0][1], bl1, lo0);
    lo1 = MFMA16(e[1][0], bl0, lo1);  lo1 = MFMA16(e[1][1], bl1, lo1);
    hi0 = MFMA16(e[0][0], bh0, hi0);  hi0 = MFMA16(e[0][1], bh1, hi0);
    hi1 = MFMA16(e[1][0], bh0, hi1);  hi1 = MFMA16(e[1][1], bh1, hi1);
#pragma unroll
    for (int r4 = 0; r4 < 4; ++r4) {
      int row0 = r0 + w * 32 + g * 4 + r4;
      xg[(size_t)row0 * 64 + ctp * 16 + m] =
          bf16r(lo0[r4]) | (bf16r(hi0[r4]) << 16);
      int row1 = row0 + 16;
      xg[(size_t)row1 * 64 + ctp * 16 + m] =
          bf16r(lo1[r4]) | (bf16r(hi1[r4]) << 16);
    }
  }
}

// ---------------------------------------------------------------------------
// K2 (MFMA scan): 16 batches per wave, 64 blocks. Per step:
//   z^T[128 gates][16 batches] = R^T·h^T + xg   via 8× mfma_16x16x32_bf16
// A = R^T chunk n (static): lane(m,g) holds A[row=gate'=m][k=8g+j]
//     = rec[8g+j][n*16+m]   (same k-map as B -> permutation cancels, as k1)
// B = h^T: lane(m,g) holds h[batch=m][H=8g+j] (bf16x8 = pairs 4g..4g+3)
// D/C (m89): col=lane&15=batch, row=(lane>>4)*4+reg=gate' -> gate=n*16+gate'
// Gates: i=chunks 0,1; f=2,3; g~=4,5; o=6,7 (Keras order, matches xg pack:
// u32 j holds (gate j, gate j+64)). Lane(m,g) owns batch m, H-idx {4g+r}
// (lo, reg r) and {16+4g+r} (hi) -> c stays lane-local; h exchanged via
// 8 __shfl + 4 selects into next step's B pairs.
// ---------------------------------------------------------------------------
__global__ __attribute__((amdgpu_flat_work_group_size(64, 64)))
__attribute__((amdgpu_waves_per_eu(1, 1)))
void k2_scan(const uint32_t* __restrict__ xgin, float* __restrict__ hout,
             const float* __restrict__ rec) {
  const int lane = threadIdx.x;
  const int m = lane & 15;
  const int g = lane >> 4;
  const int b0 = blockIdx.x * 16;

  // A-fragments (R^T chunks), one-time
  bf16x8 a[8];
#pragma unroll
  for (int n = 0; n < 8; ++n) {
    bf16x8 t;
#pragma unroll
    for (int j = 0; j < 8; ++j)
      t[j] = (short)bf16r(rec[(size_t)(8 * g + j) * G_ + n * 16 + m]);
    a[n] = t;
  }

  // xg: u32 idx (b*T+t)*64 + n*16 + g*4 ; h out: f32 idx (b*T+t)*64 + 4g (+16)
  const uint32_t* xp = xgin + (size_t)(b0 + m) * (T_ * 64) + g * 4;
  float* hp = hout + (size_t)(b0 + m) * (T_ * 64) + g * 4;

  // exchange sources: g=0,2 read groups 0,1 ; g=1,3 read groups 2,3
  const int lane02 = m + ((g & 1) ? 32 : 0);
  const int lane13 = lane02 + 16;
  const bool glo = (g < 2);

  f32x4 c_lo = {0.f, 0.f, 0.f, 0.f}, c_hi = {0.f, 0.f, 0.f, 0.f};
  uint32_t q0 = 0, q1 = 0, q2 = 0, q3 = 0;  // h=0 initially

  auto step = [&](uint4 w0, uint4 w1, uint4 w2, uint4 w3, int t) {
    u32x4 qq = {q0, q1, q2, q3};
    bf16x8 bfrag = __builtin_bit_cast(bf16x8, qq);

    // C init: chunk n<4 from lo halves, n+4 from hi halves of the same u32s
    f32x4 z0 = {bflo(w0.x), bflo(w0.y), bflo(w0.z), bflo(w0.w)};
    f32x4 z1 = {bflo(w1.x), bflo(w1.y), bflo(w1.z), bflo(w1.w)};
    f32x4 z2 = {bflo(w2.x), bflo(w2.y), bflo(w2.z), bflo(w2.w)};
    f32x4 z3 = {bflo(w3.x), bflo(w3.y), bflo(w3.z), bflo(w3.w)};
    f32x4 z4 = {bfhi(w0.x), bfhi(w0.y), bfhi(w0.z), bfhi(w0.w)};
    f32x4 z5 = {bfhi(w1.x), bfhi(w1.y), bfhi(w1.z), bfhi(w1.w)};
    f32x4 z6 = {bfhi(w2.x), bfhi(w2.y), bfhi(w2.z), bfhi(w2.w)};
    f32x4 z7 = {bfhi(w3.x), bfhi(w3.y), bfhi(w3.z), bfhi(w3.w)};

    z0 = MFMA16(a[0], bfrag, z0);  // i, H {4g+r}
    z1 = MFMA16(a[1], bfrag, z1);  // i, H {16+4g+r}
    z2 = MFMA16(a[2], bfrag, z2);  // f lo
    z3 = MFMA16(a[3], bfrag, z3);  // f hi
    z4 = MFMA16(a[4], bfrag, z4);  // g~ lo
    z5 = MFMA16(a[5], bfrag, z5);  // g~ hi
    z6 = MFMA16(a[6], bfrag, z6);  // o lo
    z7 = MFMA16(a[7], bfrag, z7);  // o hi

    f32x4 h_lo, h_hi;
#pragma unroll
    for (int r = 0; r < 4; ++r) {
      float i1 = fsig(z0[r]), i2 = fsig(z1[r]);
      float f1 = fsig(z2[r]), f2 = fsig(z3[r]);
      float g1 = ftanh(z4[r]), g2 = ftanh(z5[r]);
      float o1 = fsig(z6[r]), o2 = fsig(z7[r]);
      c_lo[r] = f1 * c_lo[r] + i1 * g1;
      c_hi[r] = f2 * c_hi[r] + i2 * g2;
      h_lo[r] = o1 * ftanh(c_lo[r]);
      h_hi[r] = o2 * ftanh(c_hi[r]);
    }

    // fp32 h for k3 (2 x 16B per lane)
    *(float4*)(hp + (size_t)t * 64) = (float4){h_lo[0], h_lo[1], h_lo[2], h_lo[3]};
    *(float4*)(hp + (size_t)t * 64 + 16) = (float4){h_hi[0], h_hi[1], h_hi[2], h_hi[3]};

    // pack pairs: pr0=(H4g,4g+1)->pair 2g, pr1->2g+1, pr2->2g+8, pr3->2g+9
    uint32_t pr0 = bf16r(h_lo[0]) | (bf16r(h_lo[1]) << 16);
    uint32_t pr1 = bf16r(h_lo[2]) | (bf16r(h_lo[3]) << 16);
    uint32_t pr2 = bf16r(h_hi[0]) | (bf16r(h_hi[1]) << 16);
    uint32_t pr3 = bf16r(h_hi[2]) | (bf16r(h_hi[3]) << 16);

    // dest (m,g) needs pairs 4g..4g+3:
    //  g=0:{0..3}=pr0,pr1 of grp0,grp1   g=1:{4..7}=pr0,pr1 of grp2,grp3
    //  g=2:{8..11}=pr2,pr3 of grp0,grp1  g=3:{12..15}=pr2,pr3 of grp2,grp3
    uint32_t x0 = __shfl(pr0, lane02), x1 = __shfl(pr1, lane02);
    uint32_t x2 = __shfl(pr0, lane13), x3 = __shfl(pr1, lane13);
    uint32_t y0 = __shfl(pr2, lane02), y1 = __shfl(pr3, lane02);
    uint32_t y2 = __shfl(pr2, lane13), y3 = __shfl(pr3, lane13);
    q0 = glo ? x0 : y0;  q1 = glo ? x1 : y1;
    q2 = glo ? x2 : y2;  q3 = glo ? x3 : y3;
  };

#define LD4(p, tt, d0, d1, d2, d3)                                   \
  uint4 d0 = *(const uint4*)((p) + (size_t)((tt) & 511) * 64);       \
  uint4 d1 = *(const uint4*)((p) + (size_t)((tt) & 511) * 64 + 16);  \
  uint4 d2 = *(const uint4*)((p) + (size_t)((tt) & 511) * 64 + 32);  \
  uint4 d3 = *(const uint4*)((p) + (size_t)((tt) & 511) * 64 + 48);

  LD4(xp, 0, A0, A1, A2, A3)
  LD4(xp, 1, Bb0, Bb1, Bb2, Bb3)
  for (int t = 0; t < T_; t += 2) {
    LD4(xp, t + 2, nA0, nA1, nA2, nA3)   // wrapped tail loads unused
    step(A0, A1, A2, A3, t);
    A0 = nA0; A1 = nA1; A2 = nA2; A3 = nA3;
    LD4(xp, t + 3, nB0, nB1, nB2, nB3)
    step(Bb0, Bb1, Bb2, Bb3, t + 1);
    Bb0 = nB0; Bb1 = nB1; Bb2 = nB2; Bb3 = nB3;
  }
#undef LD4
}

// ---------------------------------------------------------------------------
// K3 (unchanged — verified r7, spill-free).
// ---------------------------------------------------------------------------
__global__ __launch_bounds__(256, 4) void k3_attn(
    const uint32_t* __restrict__ xg,
    const float* __restrict__ attnW, const float* __restrict__ attnB,
    const float* __restrict__ attnU, const float* __restrict__ Wdec,
    const float* __restrict__ bdec, float* __restrict__ out) {
  __shared__ float sSc[T_];
  __shared__ float sRed[8];
  __shared__ float sP[8][H_];
  const int tid = threadIdx.x;
  const int b = blockIdx.x;

  const uint32_t* hbase = xg + (size_t)b * (T_ * 64);

  float mysc[2];
#pragma unroll
  for (int q = 0; q < 2; ++q) {
    int t = tid + q * 256;
    const float4* hp = (const float4*)(hbase + (size_t)t * 64);

    float hv[H_];
#pragma unroll
    for (int i = 0; i < 8; ++i) {
      float4 v = hp[i];
      hv[4 * i + 0] = v.x; hv[4 * i + 1] = v.y;
      hv[4 * i + 2] = v.z; hv[4 * i + 3] = v.w;
    }

    float lat[H_];
#pragma unroll
    for (int j4 = 0; j4 < 8; ++j4) {
      float4 bv = ((const float4*)attnB)[j4];  // uniform -> s_load
      lat[4 * j4 + 0] = bv.x; lat[4 * j4 + 1] = bv.y;
      lat[4 * j4 + 2] = bv.z; lat[4 * j4 + 3] = bv.w;
    }
#pragma unroll
    for (int d = 0; d < H_; ++d) {
      float hd = hv[d];
      const float4* wr = (const float4*)(attnW + d * H_);  // uniform -> s_load
#pragma unroll
      for (int j4 = 0; j4 < 8; ++j4) {
        float4 w = wr[j4];
        lat[4 * j4 + 0] += hd * w.x;
        lat[4 * j4 + 1] += hd * w.y;
        lat[4 * j4 + 2] += hd * w.z;
        lat[4 * j4 + 3] += hd * w.w;
      }
    }
    float sc = 0.f;
#pragma unroll
    for (int j = 0; j < H_; ++j) sc += ftanh(lat[j]) * attnU[j];
    mysc[q] = sc;
  }

  float m2 = fmaxf(mysc[0], mysc[1]);
  m2 = fmaxf(m2, __shfl_xor(m2, 1));  m2 = fmaxf(m2, __shfl_xor(m2, 2));
  m2 = fmaxf(m2, __shfl_xor(m2, 4));  m2 = fmaxf(m2, __shfl_xor(m2, 8));
  m2 = fmaxf(m2, __shfl_xor(m2, 16)); m2 = fmaxf(m2, __shfl_xor(m2, 32));
  if ((tid & 63) == 0) sRed[tid >> 6] = m2;
  __syncthreads();
  float m = fmaxf(fmaxf(sRed[0], sRed[1]), fmaxf(sRed[2], sRed[3]));
  float e0 = __expf(mysc[0] - m), e1 = __expf(mysc[1] - m);
  sSc[tid] = e0;
  sSc[tid + 256] = e1;
  float s2 = e0 + e1;
  s2 += __shfl_xor(s2, 1);  s2 += __shfl_xor(s2, 2);
  s2 += __shfl_xor(s2, 4);  s2 += __shfl_xor(s2, 8);
  s2 += __shfl_xor(s2, 16); s2 += __shfl_xor(s2, 32);
  if ((tid & 63) == 0) sRed[4 + (tid >> 6)] = s2;
  __syncthreads();
  float l = (sRed[4] + sRed[5]) + (sRed[6] + sRed[7]);

  const int j = tid & 31;
  const int grp = tid >> 5;  // 0..7
  float p = 0.f;
  for (int tt = grp * 64; tt < grp * 64 + 64; ++tt) {
    p += sSc[tt] * ((const float*)(hbase + (size_t)tt * 64))[j];
  }
  sP[grp][j] = p;
  __syncthreads();

  if (tid < H_) {
    float pooled = 0.f;
#pragma unroll
    for (int g = 0; g < 8; ++g) pooled += sP[g][tid];
    pooled /= l;
    float h511 = ((const float*)(hbase + (size_t)511 * 64))[tid];
    float val = h511 * Wdec[tid] + pooled * Wdec[H_ + tid];
    val += __shfl_xor(val, 1);  val += __shfl_xor(val, 2);
    val += __shfl_xor(val, 4);  val += __shfl_xor(val, 8);
    val += __shfl_xor(val, 16);
    if (tid == 0) out[b] = fsig(val + bdec[0]);
  }
}

extern "C" void kernel_launch(void* const* d_in, const int* in_sizes, int n_in,
                              void* d_out, int out_size, void* d_ws, size_t ws_size,
                              hipStream_t stream) {
  const float* x     = (const float*)d_in[0];
  const float* Wenc  = (const float*)d_in[1];
  const float* benc  = (const float*)d_in[2];
  const float* kern  = (const float*)d_in[3];
  const float* rec   = (const float*)d_in[4];
  const float* bias  = (const float*)d_in[5];
  const float* attnW = (const float*)d_in[6];
  const float* attnB = (const float*)d_in[7];
  const float* attnU = (const float*)d_in[8];
  const float* Wdec  = (const float*)d_in[9];
  const float* bdec  = (const float*)d_in[10];

  uint32_t* xg = (uint32_t*)d_ws;  // [B][T][64] packed bf16 pairs = 128 MiB

  hipLaunchKernelGGL(k1_mfma, dim3((B_ * T_) / 128), dim3(256), 0, stream,
                     x, Wenc, benc, kern, bias, xg);
  hipLaunchKernelGGL(k2_scan, dim3(B_ / 16), dim3(64), 0, stream,
                     xg, (float*)d_ws, rec);
  hipLaunchKernelGGL(k3_attn, dim3(B_), dim3(256), 0, stream,
                     xg, attnW, attnB, attnU, Wdec, bdec, (float*)d_out);
}

// Round 17
// 551.557 us; speedup vs baseline: 1.8311x; 1.8311x over previous
//
#include <hip/hip_runtime.h>
#include <stdint.h>

#define B_ 1024
#define T_ 512
#define F_ 64
#define H_ 32
#define G_ 128  // 4H

typedef __attribute__((ext_vector_type(8))) short bf16x8;
typedef __attribute__((ext_vector_type(4))) float f32x4;

__device__ __forceinline__ uint32_t bf16r(float f) {
  uint32_t u = __builtin_bit_cast(uint32_t, f);
  return (u + 0x7fffu + ((u >> 16) & 1u)) >> 16;  // RNE bf16
}
__device__ __forceinline__ float rl(float v, int l) {
  return __builtin_bit_cast(float, __builtin_amdgcn_readlane(__builtin_bit_cast(int, v), l));
}
__device__ __forceinline__ float fsig(float x) { return 1.f / (1.f + __expf(-x)); }
__device__ __forceinline__ float ftanh(float x) { return 2.f / (1.f + __expf(-2.f * x)) - 1.f; }
__device__ __forceinline__ float bflo(uint32_t d) { return __builtin_bit_cast(float, d << 16); }
__device__ __forceinline__ float bfhi(uint32_t d) { return __builtin_bit_cast(float, d & 0xffff0000u); }

#define MFMA16(a, b, c) __builtin_amdgcn_mfma_f32_16x16x32_bf16((a), (b), (c), 0, 0, 0)

// ---------------------------------------------------------------------------
// K1 (MFMA, unchanged — verified r6/r7): xg = pack_bf16(tanh(x@Wenc+benc)@kern+bias)
// ---------------------------------------------------------------------------
__global__ __launch_bounds__(256, 3) void k1_mfma(
    const float* __restrict__ x, const float* __restrict__ Wenc,
    const float* __restrict__ benc, const float* __restrict__ kern,
    const float* __restrict__ bias, uint32_t* __restrict__ xg) {
  __shared__ unsigned short sWt[64 * 72];   // Wenc^T bf16 [n][k], stride 72
  __shared__ unsigned short sKt[128 * 72];  // kern^T bf16 [n][k]
  __shared__ unsigned short sE[128 * 72];   // enc bf16 [row][k]
  const int tid = threadIdx.x;
  const int lane = tid & 63;
  const int w = tid >> 6;       // wave 0..3 -> rows w*32..w*32+31
  const int m = lane & 15;
  const int g = lane >> 4;      // 0..3
  const int r0 = blockIdx.x * 128;

  {  // stage Wenc^T and kern^T as bf16 (one-time)
    const int r = tid & 63;
    const int c0 = (tid >> 6) * 16;
#pragma unroll
    for (int q = 0; q < 4; ++q) {
      float4 v = *(const float4*)(Wenc + (size_t)r * F_ + c0 + q * 4);
      sWt[(c0 + q * 4 + 0) * 72 + r] = (unsigned short)bf16r(v.x);
      sWt[(c0 + q * 4 + 1) * 72 + r] = (unsigned short)bf16r(v.y);
      sWt[(c0 + q * 4 + 2) * 72 + r] = (unsigned short)bf16r(v.z);
      sWt[(c0 + q * 4 + 3) * 72 + r] = (unsigned short)bf16r(v.w);
    }
    const int d0 = (tid >> 6) * 32;
#pragma unroll
    for (int q = 0; q < 8; ++q) {
      float4 v = *(const float4*)(kern + (size_t)r * G_ + d0 + q * 4);
      sKt[(d0 + q * 4 + 0) * 72 + r] = (unsigned short)bf16r(v.x);
      sKt[(d0 + q * 4 + 1) * 72 + r] = (unsigned short)bf16r(v.y);
      sKt[(d0 + q * 4 + 2) * 72 + r] = (unsigned short)bf16r(v.z);
      sKt[(d0 + q * 4 + 3) * 72 + r] = (unsigned short)bf16r(v.w);
    }
  }
  __syncthreads();

  bf16x8 a[2][2];
#pragma unroll
  for (int rt = 0; rt < 2; ++rt)
#pragma unroll
    for (int kh = 0; kh < 2; ++kh) {
      const float* xr = x + (size_t)(r0 + w * 32 + rt * 16 + m) * F_ + kh * 32 + g * 8;
      float4 v0 = ((const float4*)xr)[0];
      float4 v1 = ((const float4*)xr)[1];
      bf16x8 t;
      t[0] = (short)bf16r(v0.x); t[1] = (short)bf16r(v0.y);
      t[2] = (short)bf16r(v0.z); t[3] = (short)bf16r(v0.w);
      t[4] = (short)bf16r(v1.x); t[5] = (short)bf16r(v1.y);
      t[6] = (short)bf16r(v1.z); t[7] = (short)bf16r(v1.w);
      a[rt][kh] = t;
    }

#pragma unroll
  for (int ct = 0; ct < 4; ++ct) {
    float be = benc[ct * 16 + m];
    f32x4 acc0 = {be, be, be, be};
    f32x4 acc1 = {be, be, be, be};
    bf16x8 b0 = *(const bf16x8*)&sWt[(ct * 16 + m) * 72 + g * 8];
    bf16x8 b1 = *(const bf16x8*)&sWt[(ct * 16 + m) * 72 + 32 + g * 8];
    acc0 = MFMA16(a[0][0], b0, acc0);
    acc0 = MFMA16(a[0][1], b1, acc0);
    acc1 = MFMA16(a[1][0], b0, acc1);
    acc1 = MFMA16(a[1][1], b1, acc1);
#pragma unroll
    for (int r4 = 0; r4 < 4; ++r4) {
      sE[(w * 32 + g * 4 + r4) * 72 + ct * 16 + m] =
          (unsigned short)bf16r(ftanh(acc0[r4]));
      sE[(w * 32 + 16 + g * 4 + r4) * 72 + ct * 16 + m] =
          (unsigned short)bf16r(ftanh(acc1[r4]));
    }
  }
  __syncthreads();

  bf16x8 e[2][2];
#pragma unroll
  for (int rt = 0; rt < 2; ++rt)
#pragma unroll
    for (int kh = 0; kh < 2; ++kh)
      e[rt][kh] = *(const bf16x8*)&sE[(w * 32 + rt * 16 + m) * 72 + kh * 32 + g * 8];

#pragma unroll
  for (int ctp = 0; ctp < 4; ++ctp) {
    float blo = bias[ctp * 16 + m];
    float bhi = bias[64 + ctp * 16 + m];
    f32x4 lo0 = {blo, blo, blo, blo}, lo1 = {blo, blo, blo, blo};
    f32x4 hi0 = {bhi, bhi, bhi, bhi}, hi1 = {bhi, bhi, bhi, bhi};
    bf16x8 bl0 = *(const bf16x8*)&sKt[(ctp * 16 + m) * 72 + g * 8];
    bf16x8 bl1 = *(const bf16x8*)&sKt[(ctp * 16 + m) * 72 + 32 + g * 8];
    bf16x8 bh0 = *(const bf16x8*)&sKt[(64 + ctp * 16 + m) * 72 + g * 8];
    bf16x8 bh1 = *(const bf16x8*)&sKt[(64 + ctp * 16 + m) * 72 + 32 + g * 8];
    lo0 = MFMA16(e[0][0], bl0, lo0);  lo0 = MFMA16(e[0][1], bl1, lo0);
    lo1 = MFMA16(e[1][0], bl0, lo1);  lo1 = MFMA16(e[1][1], bl1, lo1);
    hi0 = MFMA16(e[0][0], bh0, hi0);  hi0 = MFMA16(e[0][1], bh1, hi0);
    hi1 = MFMA16(e[1][0], bh0, hi1);  hi1 = MFMA16(e[1][1], bh1, hi1);
#pragma unroll
    for (int r4 = 0; r4 < 4; ++r4) {
      int row0 = r0 + w * 32 + g * 4 + r4;
      xg[(size_t)row0 * 64 + ctp * 16 + m] =
          bf16r(lo0[r4]) | (bf16r(hi0[r4]) << 16);
      int row1 = row0 + 16;
      xg[(size_t)row1 * 64 + ctp * 16 + m] =
          bf16r(lo1[r4]) | (bf16r(hi1[r4]) << 16);
    }
  }
}

// ---------------------------------------------------------------------------
// K2: gate-local LSTM scan. 1 batch/wave (1024 waves). Lane j (j=lane&31)
// owns ALL FOUR gates of hidden unit j (z-cols j, 32+j, 64+j, 96+j) ->
// c_j, h_j fully lane-local: ZERO cross-lane ops in the loop (r15's two
// serial ds_bpermute exchanges deleted). 128 weights/lane held in AGPRs
// (r15-verified stash; allocator otherwise caps VGPRs at 48 and reloads).
// xg mapping: u32 j = (i_j, g~_j), u32 32+j = (f_j, o_j).
// ---------------------------------------------------------------------------
__global__ __attribute__((amdgpu_flat_work_group_size(64, 64)))
__attribute__((amdgpu_waves_per_eu(1, 1)))
void k2_scan(const uint32_t* __restrict__ xgin, float* __restrict__ hout,
             const float* __restrict__ rec) {
  const int lane = threadIdx.x;
  const int jj = lane & 31;   // hidden unit owned (lanes 32-63 duplicate 0-31)
  const int b = blockIdx.x;

#define DECL4(K) float wi##K, wf##K, wg##K, wo##K;
  DECL4(0)  DECL4(1)  DECL4(2)  DECL4(3)  DECL4(4)  DECL4(5)  DECL4(6)  DECL4(7)
  DECL4(8)  DECL4(9)  DECL4(10) DECL4(11) DECL4(12) DECL4(13) DECL4(14) DECL4(15)
  DECL4(16) DECL4(17) DECL4(18) DECL4(19) DECL4(20) DECL4(21) DECL4(22) DECL4(23)
  DECL4(24) DECL4(25) DECL4(26) DECL4(27) DECL4(28) DECL4(29) DECL4(30) DECL4(31)
#undef DECL4

#define STASH4(K) { \
    float t0 = rec[K * G_ + jj]; \
    float t1 = rec[K * G_ + 32 + jj]; \
    float t2 = rec[K * G_ + 64 + jj]; \
    float t3 = rec[K * G_ + 96 + jj]; \
    asm volatile("v_accvgpr_write_b32 %0, %1" : "=a"(wi##K) : "v"(t0)); \
    asm volatile("v_accvgpr_write_b32 %0, %1" : "=a"(wf##K) : "v"(t1)); \
    asm volatile("v_accvgpr_write_b32 %0, %1" : "=a"(wg##K) : "v"(t2)); \
    asm volatile("v_accvgpr_write_b32 %0, %1" : "=a"(wo##K) : "v"(t3)); }
  STASH4(0)  STASH4(1)  STASH4(2)  STASH4(3)  STASH4(4)  STASH4(5)  STASH4(6)  STASH4(7)
  STASH4(8)  STASH4(9)  STASH4(10) STASH4(11) STASH4(12) STASH4(13) STASH4(14) STASH4(15)
  STASH4(16) STASH4(17) STASH4(18) STASH4(19) STASH4(20) STASH4(21) STASH4(22) STASH4(23)
  STASH4(24) STASH4(25) STASH4(26) STASH4(27) STASH4(28) STASH4(29) STASH4(30) STASH4(31)
#undef STASH4

  const uint32_t* xp0 = xgin + (size_t)b * (T_ * 64) + jj;        // (i,g~)
  const uint32_t* xp1 = xgin + (size_t)b * (T_ * 64) + 32 + jj;   // (f,o)
  float* hst = hout + (size_t)b * (T_ * 64);

  float h = 0.f, c = 0.f;

  auto step = [&](uint32_t w0, uint32_t w1, int t) {
    float zi = bflo(w0), zg = bfhi(w0);
    float zf = bflo(w1), zo = bfhi(w1);
#define AC(K) { float s = rl(h, K); float vi, vf, vg, vo; \
    asm volatile("v_accvgpr_read_b32 %0, %1" : "=v"(vi) : "a"(wi##K)); \
    asm volatile("v_accvgpr_read_b32 %0, %1" : "=v"(vf) : "a"(wf##K)); \
    asm volatile("v_accvgpr_read_b32 %0, %1" : "=v"(vg) : "a"(wg##K)); \
    asm volatile("v_accvgpr_read_b32 %0, %1" : "=v"(vo) : "a"(wo##K)); \
    zi = fmaf(s, vi, zi); zf = fmaf(s, vf, zf); \
    zg = fmaf(s, vg, zg); zo = fmaf(s, vo, zo); }
    AC(0)  AC(1)  AC(2)  AC(3)  AC(4)  AC(5)  AC(6)  AC(7)
    AC(8)  AC(9)  AC(10) AC(11) AC(12) AC(13) AC(14) AC(15)
    AC(16) AC(17) AC(18) AC(19) AC(20) AC(21) AC(22) AC(23)
    AC(24) AC(25) AC(26) AC(27) AC(28) AC(29) AC(30) AC(31)
#undef AC

    float i_ = fsig(zi);
    float f_ = fsig(zf);
    float g_ = ftanh(zg);
    float o_ = fsig(zo);
    c = f_ * c + i_ * g_;
    h = o_ * ftanh(c);

    if (lane < 32) hst[(size_t)t * 64 + lane] = h;  // fp32 h for k3
  };

  uint32_t p0[4], p1[4];
#pragma unroll
  for (int i = 0; i < 4; ++i) { p0[i] = xp0[i * 64]; p1[i] = xp1[i * 64]; }
  for (int tb = 0; tb < T_; tb += 4) {
    uint32_t n0[4], n1[4];
#pragma unroll
    for (int i = 0; i < 4; ++i) {               // tail wrap reads unused
      n0[i] = xp0[((tb + 4 + i) & 511) * 64];
      n1[i] = xp1[((tb + 4 + i) & 511) * 64];
    }
#pragma unroll
    for (int i = 0; i < 4; ++i) step(p0[i], p1[i], tb + i);
#pragma unroll
    for (int i = 0; i < 4; ++i) { p0[i] = n0[i]; p1[i] = n1[i]; }
  }
}

// ---------------------------------------------------------------------------
// K3 (unchanged — verified r7, spill-free).
// ---------------------------------------------------------------------------
__global__ __launch_bounds__(256, 4) void k3_attn(
    const uint32_t* __restrict__ xg,
    const float* __restrict__ attnW, const float* __restrict__ attnB,
    const float* __restrict__ attnU, const float* __restrict__ Wdec,
    const float* __restrict__ bdec, float* __restrict__ out) {
  __shared__ float sSc[T_];
  __shared__ float sRed[8];
  __shared__ float sP[8][H_];
  const int tid = threadIdx.x;
  const int b = blockIdx.x;

  const uint32_t* hbase = xg + (size_t)b * (T_ * 64);

  float mysc[2];
#pragma unroll
  for (int q = 0; q < 2; ++q) {
    int t = tid + q * 256;
    const float4* hp = (const float4*)(hbase + (size_t)t * 64);

    float hv[H_];
#pragma unroll
    for (int i = 0; i < 8; ++i) {
      float4 v = hp[i];
      hv[4 * i + 0] = v.x; hv[4 * i + 1] = v.y;
      hv[4 * i + 2] = v.z; hv[4 * i + 3] = v.w;
    }

    float lat[H_];
#pragma unroll
    for (int j4 = 0; j4 < 8; ++j4) {
      float4 bv = ((const float4*)attnB)[j4];  // uniform -> s_load
      lat[4 * j4 + 0] = bv.x; lat[4 * j4 + 1] = bv.y;
      lat[4 * j4 + 2] = bv.z; lat[4 * j4 + 3] = bv.w;
    }
#pragma unroll
    for (int d = 0; d < H_; ++d) {
      float hd = hv[d];
      const float4* wr = (const float4*)(attnW + d * H_);  // uniform -> s_load
#pragma unroll
      for (int j4 = 0; j4 < 8; ++j4) {
        float4 w = wr[j4];
        lat[4 * j4 + 0] += hd * w.x;
        lat[4 * j4 + 1] += hd * w.y;
        lat[4 * j4 + 2] += hd * w.z;
        lat[4 * j4 + 3] += hd * w.w;
      }
    }
    float sc = 0.f;
#pragma unroll
    for (int j = 0; j < H_; ++j) sc += ftanh(lat[j]) * attnU[j];
    mysc[q] = sc;
  }

  float m2 = fmaxf(mysc[0], mysc[1]);
  m2 = fmaxf(m2, __shfl_xor(m2, 1));  m2 = fmaxf(m2, __shfl_xor(m2, 2));
  m2 = fmaxf(m2, __shfl_xor(m2, 4));  m2 = fmaxf(m2, __shfl_xor(m2, 8));
  m2 = fmaxf(m2, __shfl_xor(m2, 16)); m2 = fmaxf(m2, __shfl_xor(m2, 32));
  if ((tid & 63) == 0) sRed[tid >> 6] = m2;
  __syncthreads();
  float m = fmaxf(fmaxf(sRed[0], sRed[1]), fmaxf(sRed[2], sRed[3]));
  float e0 = __expf(mysc[0] - m), e1 = __expf(mysc[1] - m);
  sSc[tid] = e0;
  sSc[tid + 256] = e1;
  float s2 = e0 + e1;
  s2 += __shfl_xor(s2, 1);  s2 += __shfl_xor(s2, 2);
  s2 += __shfl_xor(s2, 4);  s2 += __shfl_xor(s2, 8);
  s2 += __shfl_xor(s2, 16); s2 += __shfl_xor(s2, 32);
  if ((tid & 63) == 0) sRed[4 + (tid >> 6)] = s2;
  __syncthreads();
  float l = (sRed[4] + sRed[5]) + (sRed[6] + sRed[7]);

  const int j = tid & 31;
  const int grp = tid >> 5;  // 0..7
  float p = 0.f;
  for (int tt = grp * 64; tt < grp * 64 + 64; ++tt) {
    p += sSc[tt] * ((const float*)(hbase + (size_t)tt * 64))[j];
  }
  sP[grp][j] = p;
  __syncthreads();

  if (tid < H_) {
    float pooled = 0.f;
#pragma unroll
    for (int g = 0; g < 8; ++g) pooled += sP[g][tid];
    pooled /= l;
    float h511 = ((const float*)(hbase + (size_t)511 * 64))[tid];
    float val = h511 * Wdec[tid] + pooled * Wdec[H_ + tid];
    val += __shfl_xor(val, 1);  val += __shfl_xor(val, 2);
    val += __shfl_xor(val, 4);  val += __shfl_xor(val, 8);
    val += __shfl_xor(val, 16);
    if (tid == 0) out[b] = fsig(val + bdec[0]);
  }
}

extern "C" void kernel_launch(void* const* d_in, const int* in_sizes, int n_in,
                              void* d_out, int out_size, void* d_ws, size_t ws_size,
                              hipStream_t stream) {
  const float* x     = (const float*)d_in[0];
  const float* Wenc  = (const float*)d_in[1];
  const float* benc  = (const float*)d_in[2];
  const float* kern  = (const float*)d_in[3];
  const float* rec   = (const float*)d_in[4];
  const float* bias  = (const float*)d_in[5];
  const float* attnW = (const float*)d_in[6];
  const float* attnB = (const float*)d_in[7];
  const float* attnU = (const float*)d_in[8];
  const float* Wdec  = (const float*)d_in[9];
  const float* bdec  = (const float*)d_in[10];

  uint32_t* xg = (uint32_t*)d_ws;  // [B][T][64] packed bf16 pairs = 128 MiB

  hipLaunchKernelGGL(k1_mfma, dim3((B_ * T_) / 128), dim3(256), 0, stream,
                     x, Wenc, benc, kern, bias, xg);
  hipLaunchKernelGGL(k2_scan, dim3(B_), dim3(64), 0, stream,
                     xg, (float*)d_ws, rec);
  hipLaunchKernelGGL(k3_attn, dim3(B_), dim3(256), 0, stream,
                     xg, attnW, attnB, attnU, Wdec, bdec, (float*)d_out);
}